// Round 7
// baseline (715.199 us; speedup 1.0000x reference)
//
#include <hip/hip_runtime.h>
#include <hip/hip_bf16.h>
#include <stdint.h>

typedef __bf16 bf16x8 __attribute__((ext_vector_type(8)));
typedef float f32x4 __attribute__((ext_vector_type(4)));

// ---- ws element offsets (ushort) ----  (R1-proven layout)
#define WS_WIH 0          // [384][128]
#define WS_WHH 49152      // [384][128]
#define WS_HENC 98304     // [64][256]
#define WS_DEC 114688     // [16][128] rows 5..15 zero
#define WS_TOTAL 116736

// ---- LDS byte offsets ----
#define LDS_X  0          // [32][256B] bf16 swizzled; x=[E1|E2], later h_new
#define LDS_H  8192       // [32][256B] bf16 swizzled
#define LDS_SZ 16384

__device__ __forceinline__ unsigned short f2bf(float f) {
    unsigned u = __float_as_uint(f);
    unsigned r = (u + 0x7FFFu + ((u >> 16) & 1u)) >> 16;   // RNE
    return (unsigned short)r;
}

__device__ __forceinline__ unsigned cvt_pk_bf16(float a, float b) {
    unsigned r;
    asm("v_cvt_pk_bf16_f32 %0, %1, %2" : "=v"(r) : "v"(a), "v"(b));
    return r;
}

__device__ __forceinline__ float fast_rcp(float x) { return __builtin_amdgcn_rcpf(x); }
__device__ __forceinline__ float sigmf(float x) { return fast_rcp(1.0f + __expf(-x)); }
__device__ __forceinline__ float tanh_fast(float x) {
    float t = __expf(-2.0f * fabsf(x));
    float r = (1.0f - t) * fast_rcp(1.0f + t);
    return copysignf(r, x);
}

__global__ void convert_weights_kernel(const float* __restrict__ wih,
                                       const float* __restrict__ whh,
                                       const float* __restrict__ henc,
                                       const float* __restrict__ dec,
                                       unsigned short* __restrict__ ws) {
    int i = blockIdx.x * 256 + threadIdx.x;
    if (i >= WS_TOTAL) return;
    float v;
    if (i < WS_WHH)        v = wih[i];
    else if (i < WS_HENC)  v = whh[i - WS_WHH];
    else if (i < WS_DEC)   v = henc[i - WS_HENC];
    else { int d = i - WS_DEC; v = (d < 640) ? dec[d] : 0.0f; }
    ws[i] = f2bf(v);
}

// ================= Fused kernel: E1 + E2 + gates + GRU + decoder =================
// 32 rows/block, 4 waves. E2 recomputed in-kernel (R4-proven path); no global roundtrip.
__launch_bounds__(256, 3)
__global__ void gru_kernel(const float* __restrict__ pos,
                           const float* __restrict__ h_other,
                           const float* __restrict__ h,
                           const float* __restrict__ enc_W,
                           const float* __restrict__ enc_b,
                           const float* __restrict__ henc_b,
                           const float* __restrict__ b_ih,
                           const float* __restrict__ b_hh,
                           const float* __restrict__ dec_b,
                           const unsigned short* __restrict__ ws,
                           float* __restrict__ out,
                           float* __restrict__ hnew,
                           int N) {
    __shared__ char sm[LDS_SZ];
    const int tid = threadIdx.x;
    const int w   = tid >> 6;
    const int l   = tid & 63;
    const int lg  = l >> 4;
    const int ln  = l & 15;
    const int r0  = blockIdx.x * 32;

    // ---------------- stage: h -> LDS_H, E1 -> LDS_X cols 0..63 ----------------
    #pragma unroll
    for (int j = 0; j < 4; ++j) {
        int e0  = (tid + 256 * j) * 4;
        int row = e0 >> 7;
        int col = e0 & 127;
        int grow = r0 + row; if (grow > N - 1) grow = N - 1;
        float4 v = *reinterpret_cast<const float4*>(h + (size_t)grow * 128 + col);
        uint2 p;
        p.x = cvt_pk_bf16(v.x, v.y);
        p.y = cvt_pk_bf16(v.z, v.w);
        int boff = LDS_H + row * 256 + ((col * 2) ^ ((row & 7) << 4));
        *reinterpret_cast<uint2*>(sm + boff) = p;
    }
    {
        int row = tid >> 3;
        int c0  = (tid & 7) * 8;
        int grow = r0 + row; if (grow > N - 1) grow = N - 1;
        float p0 = pos[(size_t)grow * 2 + 0];
        float p1 = pos[(size_t)grow * 2 + 1];
        #pragma unroll
        for (int q = 0; q < 4; ++q) {
            int c = c0 + q * 2;
            float v0 = fmaxf(p0 * enc_W[c * 2]     + p1 * enc_W[c * 2 + 1] + enc_b[c], 0.f);
            float v1 = fmaxf(p0 * enc_W[c * 2 + 2] + p1 * enc_W[c * 2 + 3] + enc_b[c + 1], 0.f);
            unsigned pk = cvt_pk_bf16(v0, v1);
            int boff = LDS_X + row * 256 + ((c * 2) ^ ((row & 7) << 4));
            *reinterpret_cast<unsigned*>(sm + boff) = pk;
        }
    }

    // ---------------- E2 = relu(h_other @ henc_W.T + b) -> LDS_X cols 64..127 ----------------
    // (R4-proven path: wave w owns E2 cols [16w,16w+16); A direct from global f32; B from ws.)
    {
        bf16x8 Bh[8];
        const unsigned short* hb = ws + WS_HENC + (size_t)(16 * w + ln) * 256;
        #pragma unroll
        for (int ks = 0; ks < 8; ++ks)
            Bh[ks] = *reinterpret_cast<const bf16x8*>(hb + ks * 32 + lg * 8);

        f32x4 e2[2];
        #pragma unroll
        for (int mt = 0; mt < 2; ++mt) e2[mt] = (f32x4){0.f, 0.f, 0.f, 0.f};
        #pragma unroll
        for (int mt = 0; mt < 2; ++mt) {
            int grow = r0 + 16 * mt + ln; if (grow > N - 1) grow = N - 1;
            const float* rp = h_other + (size_t)grow * 256 + lg * 8;
            #pragma unroll
            for (int ks = 0; ks < 8; ++ks) {
                const float* ap = rp + ks * 32;
                float4 a0 = *reinterpret_cast<const float4*>(ap);
                float4 a1 = *reinterpret_cast<const float4*>(ap + 4);
                union { unsigned u[4]; bf16x8 b; } af;
                af.u[0] = cvt_pk_bf16(a0.x, a0.y);
                af.u[1] = cvt_pk_bf16(a0.z, a0.w);
                af.u[2] = cvt_pk_bf16(a1.x, a1.y);
                af.u[3] = cvt_pk_bf16(a1.z, a1.w);
                e2[mt] = __builtin_amdgcn_mfma_f32_16x16x32_bf16(af.b, Bh[ks], e2[mt], 0, 0, 0);
            }
        }
        int col = 16 * w + ln;
        float bias = henc_b[col];
        #pragma unroll
        for (int mt = 0; mt < 2; ++mt)
            #pragma unroll
            for (int i = 0; i < 4; ++i) {
                int row = 16 * mt + lg * 4 + i;
                float v = fmaxf(e2[mt][i] + bias, 0.f);
                *reinterpret_cast<unsigned short*>(
                    sm + LDS_X + row * 256 + (((64 + col) * 2) ^ ((row & 7) << 4))) = f2bf(v);
            }
    }
    __syncthreads();

    // ---------------- gates: wave w -> cols [32w,32w+32), rows 32 ----------------
    f32x4 acc[2][8];
    #pragma unroll
    for (int a = 0; a < 2; ++a)
        #pragma unroll
        for (int b = 0; b < 8; ++b) acc[a][b] = (f32x4){0.f, 0.f, 0.f, 0.f};

    const unsigned short* WIH = ws + WS_WIH;
    const unsigned short* WHH = ws + WS_WHH;

    #pragma unroll
    for (int t = 0; t < 8; ++t) {
        const int abase = (t < 4) ? LDS_X : LDS_H;
        const int kb = (t & 3) * 64;
        bf16x8 Af[2];
        #pragma unroll
        for (int mt = 0; mt < 2; ++mt) {
            int row = 16 * mt + ln;
            Af[mt] = *reinterpret_cast<const bf16x8*>(
                sm + abase + row * 256 + ((kb + lg * 16) ^ ((row & 7) << 4)));
        }
        const int kk = (t & 3) * 32 + lg * 8;

        #define MFMA_JOB(job, Wptr, ob) { \
            bf16x8 bfr = *reinterpret_cast<const bf16x8*>((Wptr) + (size_t)((ob) + ln) * 128 + kk); \
            acc[0][job] = __builtin_amdgcn_mfma_f32_16x16x32_bf16(Af[0], bfr, acc[0][job], 0, 0, 0); \
            acc[1][job] = __builtin_amdgcn_mfma_f32_16x16x32_bf16(Af[1], bfr, acc[1][job], 0, 0, 0); }

        if (t < 4) {
            MFMA_JOB(0, WIH, 32 * w);
            MFMA_JOB(1, WIH, 32 * w + 16);
            MFMA_JOB(2, WIH, 128 + 32 * w);
            MFMA_JOB(3, WIH, 144 + 32 * w);
            MFMA_JOB(4, WIH, 256 + 32 * w);
            MFMA_JOB(5, WIH, 272 + 32 * w);
        } else {
            MFMA_JOB(0, WHH, 32 * w);
            MFMA_JOB(1, WHH, 32 * w + 16);
            MFMA_JOB(2, WHH, 128 + 32 * w);
            MFMA_JOB(3, WHH, 144 + 32 * w);
            MFMA_JOB(6, WHH, 256 + 32 * w);
            MFMA_JOB(7, WHH, 272 + 32 * w);
        }
        #undef MFMA_JOB
    }

    // all waves must finish reading LDS_X/LDS_H before epilogue overwrites LDS_X
    __syncthreads();

    // ---------------- GRU epilogue (register-local; h f32 from L2) ----------------
    #pragma unroll
    for (int jt = 0; jt < 2; ++jt) {
        int j = 32 * w + 16 * jt + ln;
        float br  = b_ih[j] + b_hh[j];
        float bz  = b_ih[128 + j] + b_hh[128 + j];
        float bxn = b_ih[256 + j];
        float bhn = b_hh[256 + j];
        #pragma unroll
        for (int mt = 0; mt < 2; ++mt)
            #pragma unroll
            for (int i = 0; i < 4; ++i) {
                int row = mt * 16 + lg * 4 + i;
                int grow = r0 + row;
                int lrow = (grow < N) ? grow : (N - 1);
                float r  = sigmf(acc[mt][jt][i] + br);
                float z  = sigmf(acc[mt][2 + jt][i] + bz);
                float xn = acc[mt][4 + jt][i] + bxn;
                float hn = acc[mt][6 + jt][i] + bhn;
                float nn = tanh_fast(xn + r * hn);
                float hp = h[(size_t)lrow * 128 + j];
                float hv = (1.0f - z) * nn + z * hp;
                if (grow < N) hnew[(size_t)grow * 128 + j] = hv;
                *reinterpret_cast<unsigned short*>(
                    sm + LDS_X + row * 256 + ((j * 2) ^ ((row & 7) << 4))) = f2bf(hv);
            }
    }
    __syncthreads();

    // ---------------- decoder: out = h_new @ dec_W.T + dec_b ----------------
    if (w < 2) {
        f32x4 oc = (f32x4){0.f, 0.f, 0.f, 0.f};
        #pragma unroll
        for (int ks = 0; ks < 4; ++ks) {
            int row = 16 * w + ln;
            bf16x8 af = *reinterpret_cast<const bf16x8*>(
                sm + LDS_X + row * 256 + ((ks * 64 + lg * 16) ^ ((row & 7) << 4)));
            bf16x8 bf = *reinterpret_cast<const bf16x8*>(ws + WS_DEC + ln * 128 + ks * 32 + lg * 8);
            oc = __builtin_amdgcn_mfma_f32_16x16x32_bf16(af, bf, oc, 0, 0, 0);
        }
        if (ln < 5) {
            float bias = dec_b[ln];
            #pragma unroll
            for (int i = 0; i < 4; ++i) {
                int grow = r0 + 16 * w + lg * 4 + i;
                if (grow < N) out[(size_t)grow * 5 + ln] = oc[i] + bias;
            }
        }
    }
}

extern "C" void kernel_launch(void* const* d_in, const int* in_sizes, int n_in,
                              void* d_out, int out_size, void* d_ws, size_t ws_size,
                              hipStream_t stream) {
    const float* pos     = (const float*)d_in[0];
    const float* h_other = (const float*)d_in[1];
    const float* h       = (const float*)d_in[2];
    const float* enc_W   = (const float*)d_in[3];
    const float* enc_b   = (const float*)d_in[4];
    const float* henc_W  = (const float*)d_in[5];
    const float* henc_b  = (const float*)d_in[6];
    const float* W_ih    = (const float*)d_in[7];
    const float* b_ih    = (const float*)d_in[8];
    const float* W_hh    = (const float*)d_in[9];
    const float* b_hh    = (const float*)d_in[10];
    const float* dec_W   = (const float*)d_in[11];
    const float* dec_b   = (const float*)d_in[12];

    int N = in_sizes[0] / 2;
    unsigned short* ws = (unsigned short*)d_ws;
    float* out  = (float*)d_out;
    float* hnew = out + (size_t)N * 5;

    hipLaunchKernelGGL(convert_weights_kernel, dim3((WS_TOTAL + 255) / 256), dim3(256), 0, stream,
                       W_ih, W_hh, henc_W, dec_W, ws);
    hipLaunchKernelGGL(gru_kernel, dim3((N + 31) / 32), dim3(256), 0, stream,
                       pos, h_other, h, enc_W, enc_b, henc_b, b_ih, b_hh, dec_b,
                       ws, out, hnew, N);
}

// Round 8
// 556.347 us; speedup vs baseline: 1.2855x; 1.2855x over previous
//
#include <hip/hip_runtime.h>
#include <hip/hip_bf16.h>
#include <stdint.h>

typedef __bf16 bf16x8 __attribute__((ext_vector_type(8)));
typedef float f32x4 __attribute__((ext_vector_type(4)));

// ---- ws element offsets (ushort) ----  (R1-proven layout)
#define WS_WIH 0          // [384][128]
#define WS_WHH 49152      // [384][128]
#define WS_HENC 98304     // [64][256]
#define WS_DEC 114688     // [16][128] rows 5..15 zero
#define WS_TOTAL 116736

// ---- LDS byte offsets ----
#define LDS_X  0          // [64][256B] bf16 swizzled; x=[E1|E2], later h_new
#define LDS_H  16384      // [64][256B] bf16 swizzled (h tile)
#define LDS_SZ 32768

__device__ __forceinline__ unsigned short f2bf(float f) {
    unsigned u = __float_as_uint(f);
    unsigned r = (u + 0x7FFFu + ((u >> 16) & 1u)) >> 16;   // RNE
    return (unsigned short)r;
}
__device__ __forceinline__ float bf2f(unsigned short u) {
    return __uint_as_float(((unsigned)u) << 16);
}

__device__ __forceinline__ unsigned cvt_pk_bf16(float a, float b) {
    unsigned r;
    asm("v_cvt_pk_bf16_f32 %0, %1, %2" : "=v"(r) : "v"(a), "v"(b));
    return r;
}

__device__ __forceinline__ float fast_rcp(float x) { return __builtin_amdgcn_rcpf(x); }
__device__ __forceinline__ float sigmf(float x) { return fast_rcp(1.0f + __expf(-x)); }
__device__ __forceinline__ float tanh_fast(float x) {
    float t = __expf(-2.0f * fabsf(x));
    float r = (1.0f - t) * fast_rcp(1.0f + t);
    return copysignf(r, x);
}

__global__ void convert_weights_kernel(const float* __restrict__ wih,
                                       const float* __restrict__ whh,
                                       const float* __restrict__ henc,
                                       const float* __restrict__ dec,
                                       unsigned short* __restrict__ ws) {
    int i = blockIdx.x * 256 + threadIdx.x;
    if (i >= WS_TOTAL) return;
    float v;
    if (i < WS_WHH)        v = wih[i];
    else if (i < WS_HENC)  v = whh[i - WS_WHH];
    else if (i < WS_DEC)   v = henc[i - WS_HENC];
    else { int d = i - WS_DEC; v = (d < 640) ? dec[d] : 0.0f; }
    ws[i] = f2bf(v);
}

// ================= Fused kernel: 64 rows/block, 4 waves =================
// R1 structure + R4's E2-direct-global (no LDS_HO) + epilogue h from LDS bf16.
__launch_bounds__(256, 2)
__global__ void fused_rnn_kernel(const float* __restrict__ pos,
                                 const float* __restrict__ h_other,
                                 const float* __restrict__ h,
                                 const float* __restrict__ enc_W,
                                 const float* __restrict__ enc_b,
                                 const float* __restrict__ henc_b,
                                 const float* __restrict__ b_ih,
                                 const float* __restrict__ b_hh,
                                 const float* __restrict__ dec_b,
                                 const unsigned short* __restrict__ ws,
                                 float* __restrict__ out,
                                 float* __restrict__ hnew,
                                 int N) {
    __shared__ char sm[LDS_SZ];
    const int tid = threadIdx.x;
    const int w   = tid >> 6;      // wave 0..3
    const int l   = tid & 63;
    const int lg  = l >> 4;
    const int ln  = l & 15;
    const int row0 = blockIdx.x * 64;

    // ---------------- Phase 0: stage h -> LDS_H, E1 -> LDS_X cols 0..63 ----------------
    #pragma unroll
    for (int j = 0; j < 8; ++j) {
        int e0  = (tid + 256 * j) * 4;
        int row = e0 >> 7;
        int col = e0 & 127;
        int grow = row0 + row; if (grow > N - 1) grow = N - 1;
        float4 v = *reinterpret_cast<const float4*>(h + (size_t)grow * 128 + col);
        uint2 p;
        p.x = cvt_pk_bf16(v.x, v.y);
        p.y = cvt_pk_bf16(v.z, v.w);
        int boff = LDS_H + row * 256 + ((col * 2) ^ ((row & 7) << 4));
        *reinterpret_cast<uint2*>(sm + boff) = p;
    }
    {
        int row = tid >> 2;
        int c0  = (tid & 3) * 16;
        int grow = row0 + row; if (grow > N - 1) grow = N - 1;
        float p0 = pos[(size_t)grow * 2 + 0];
        float p1 = pos[(size_t)grow * 2 + 1];
        #pragma unroll
        for (int q = 0; q < 8; ++q) {
            int c = c0 + q * 2;
            float v0 = fmaxf(p0 * enc_W[c * 2]     + p1 * enc_W[c * 2 + 1] + enc_b[c], 0.f);
            float v1 = fmaxf(p0 * enc_W[c * 2 + 2] + p1 * enc_W[c * 2 + 3] + enc_b[c + 1], 0.f);
            unsigned pk = cvt_pk_bf16(v0, v1);
            int boff = LDS_X + row * 256 + ((c * 2) ^ ((row & 7) << 4));
            *reinterpret_cast<unsigned*>(sm + boff) = pk;
        }
    }

    // ---------------- E2 = relu(h_other @ henc_W.T + b) -> LDS_X cols 64..127 ----------------
    // wave w owns E2 cols [16w,16w+16); A direct from global f32 (R4-proven); B from ws (L2).
    {
        bf16x8 Bh[8];
        const unsigned short* hb = ws + WS_HENC + (size_t)(16 * w + ln) * 256;
        #pragma unroll
        for (int ks = 0; ks < 8; ++ks)
            Bh[ks] = *reinterpret_cast<const bf16x8*>(hb + ks * 32 + lg * 8);

        f32x4 e2[4];
        #pragma unroll
        for (int mt = 0; mt < 4; ++mt) e2[mt] = (f32x4){0.f, 0.f, 0.f, 0.f};
        #pragma unroll
        for (int mt = 0; mt < 4; ++mt) {
            int grow = row0 + 16 * mt + ln; if (grow > N - 1) grow = N - 1;
            const float* rp = h_other + (size_t)grow * 256 + lg * 8;
            #pragma unroll
            for (int ks = 0; ks < 8; ++ks) {
                const float* ap = rp + ks * 32;
                float4 a0 = *reinterpret_cast<const float4*>(ap);
                float4 a1 = *reinterpret_cast<const float4*>(ap + 4);
                union { unsigned u[4]; bf16x8 b; } af;
                af.u[0] = cvt_pk_bf16(a0.x, a0.y);
                af.u[1] = cvt_pk_bf16(a0.z, a0.w);
                af.u[2] = cvt_pk_bf16(a1.x, a1.y);
                af.u[3] = cvt_pk_bf16(a1.z, a1.w);
                e2[mt] = __builtin_amdgcn_mfma_f32_16x16x32_bf16(af.b, Bh[ks], e2[mt], 0, 0, 0);
            }
        }
        int col = 16 * w + ln;
        float bias = henc_b[col];
        #pragma unroll
        for (int mt = 0; mt < 4; ++mt)
            #pragma unroll
            for (int i = 0; i < 4; ++i) {
                int row = 16 * mt + lg * 4 + i;
                float v = fmaxf(e2[mt][i] + bias, 0.f);
                *reinterpret_cast<unsigned short*>(
                    sm + LDS_X + row * 256 + (((64 + col) * 2) ^ ((row & 7) << 4))) = f2bf(v);
            }
    }
    __syncthreads();   // barrier 1: X (E1+E2) and H complete

    // ---------------- gates: wave w -> cols [32w,32w+32) x 64 rows ----------------
    f32x4 acc[4][8];
    #pragma unroll
    for (int a = 0; a < 4; ++a)
        #pragma unroll
        for (int b = 0; b < 8; ++b) acc[a][b] = (f32x4){0.f, 0.f, 0.f, 0.f};

    const unsigned short* WIH = ws + WS_WIH;
    const unsigned short* WHH = ws + WS_WHH;

    #pragma unroll
    for (int t = 0; t < 8; ++t) {
        const int abase = (t < 4) ? LDS_X : LDS_H;
        const int kb = (t & 3) * 64;
        bf16x8 Af[4];
        #pragma unroll
        for (int mt = 0; mt < 4; ++mt) {
            int row = 16 * mt + ln;
            Af[mt] = *reinterpret_cast<const bf16x8*>(
                sm + abase + row * 256 + ((kb + lg * 16) ^ ((row & 7) << 4)));
        }
        const int kk = (t & 3) * 32 + lg * 8;

        #define MFMA_JOB(job, Wptr, ob) { \
            bf16x8 bfr = *reinterpret_cast<const bf16x8*>((Wptr) + (size_t)((ob) + ln) * 128 + kk); \
            acc[0][job] = __builtin_amdgcn_mfma_f32_16x16x32_bf16(Af[0], bfr, acc[0][job], 0, 0, 0); \
            acc[1][job] = __builtin_amdgcn_mfma_f32_16x16x32_bf16(Af[1], bfr, acc[1][job], 0, 0, 0); \
            acc[2][job] = __builtin_amdgcn_mfma_f32_16x16x32_bf16(Af[2], bfr, acc[2][job], 0, 0, 0); \
            acc[3][job] = __builtin_amdgcn_mfma_f32_16x16x32_bf16(Af[3], bfr, acc[3][job], 0, 0, 0); }

        if (t < 4) {
            MFMA_JOB(0, WIH, 32 * w);
            MFMA_JOB(1, WIH, 32 * w + 16);
            MFMA_JOB(2, WIH, 128 + 32 * w);
            MFMA_JOB(3, WIH, 144 + 32 * w);
            MFMA_JOB(4, WIH, 256 + 32 * w);
            MFMA_JOB(5, WIH, 272 + 32 * w);
        } else {
            MFMA_JOB(0, WHH, 32 * w);
            MFMA_JOB(1, WHH, 32 * w + 16);
            MFMA_JOB(2, WHH, 128 + 32 * w);
            MFMA_JOB(3, WHH, 144 + 32 * w);
            MFMA_JOB(6, WHH, 256 + 32 * w);
            MFMA_JOB(7, WHH, 272 + 32 * w);
        }
        #undef MFMA_JOB
    }

    __syncthreads();   // barrier 2 (R6 lesson): gate reads of X/H done before X overwrite

    // ---------------- GRU epilogue (register-local; h from LDS bf16) ----------------
    #pragma unroll
    for (int jt = 0; jt < 2; ++jt) {
        int j = 32 * w + 16 * jt + ln;
        float br  = b_ih[j] + b_hh[j];
        float bz  = b_ih[128 + j] + b_hh[128 + j];
        float bxn = b_ih[256 + j];
        float bhn = b_hh[256 + j];
        #pragma unroll
        for (int mt = 0; mt < 4; ++mt)
            #pragma unroll
            for (int i = 0; i < 4; ++i) {
                int row = mt * 16 + lg * 4 + i;
                int grow = row0 + row;
                float r  = sigmf(acc[mt][jt][i] + br);
                float z  = sigmf(acc[mt][2 + jt][i] + bz);
                float xn = acc[mt][4 + jt][i] + bxn;
                float hn = acc[mt][6 + jt][i] + bhn;
                float nn = tanh_fast(xn + r * hn);
                unsigned short hu = *reinterpret_cast<const unsigned short*>(
                    sm + LDS_H + row * 256 + ((j * 2) ^ ((row & 7) << 4)));
                float hp = bf2f(hu);
                float hv = (1.0f - z) * nn + z * hp;
                if (grow < N) hnew[(size_t)grow * 128 + j] = hv;
                *reinterpret_cast<unsigned short*>(
                    sm + LDS_X + row * 256 + ((j * 2) ^ ((row & 7) << 4))) = f2bf(hv);
            }
    }
    __syncthreads();   // barrier 3: h_new tile complete

    // ---------------- decoder: out = h_new @ dec_W.T + dec_b ----------------
    {
        f32x4 oc = (f32x4){0.f, 0.f, 0.f, 0.f};
        #pragma unroll
        for (int ks = 0; ks < 4; ++ks) {
            int row = 16 * w + ln;
            bf16x8 af = *reinterpret_cast<const bf16x8*>(
                sm + LDS_X + row * 256 + ((ks * 64 + lg * 16) ^ ((row & 7) << 4)));
            bf16x8 bf = *reinterpret_cast<const bf16x8*>(ws + WS_DEC + ln * 128 + ks * 32 + lg * 8);
            oc = __builtin_amdgcn_mfma_f32_16x16x32_bf16(af, bf, oc, 0, 0, 0);
        }
        if (ln < 5) {
            float bias = dec_b[ln];
            #pragma unroll
            for (int i = 0; i < 4; ++i) {
                int grow = row0 + 16 * w + lg * 4 + i;
                if (grow < N) out[(size_t)grow * 5 + ln] = oc[i] + bias;
            }
        }
    }
}

extern "C" void kernel_launch(void* const* d_in, const int* in_sizes, int n_in,
                              void* d_out, int out_size, void* d_ws, size_t ws_size,
                              hipStream_t stream) {
    const float* pos     = (const float*)d_in[0];
    const float* h_other = (const float*)d_in[1];
    const float* h       = (const float*)d_in[2];
    const float* enc_W   = (const float*)d_in[3];
    const float* enc_b   = (const float*)d_in[4];
    const float* henc_W  = (const float*)d_in[5];
    const float* henc_b  = (const float*)d_in[6];
    const float* W_ih    = (const float*)d_in[7];
    const float* b_ih    = (const float*)d_in[8];
    const float* W_hh    = (const float*)d_in[9];
    const float* b_hh    = (const float*)d_in[10];
    const float* dec_W   = (const float*)d_in[11];
    const float* dec_b   = (const float*)d_in[12];

    int N = in_sizes[0] / 2;
    unsigned short* ws = (unsigned short*)d_ws;
    float* out  = (float*)d_out;
    float* hnew = out + (size_t)N * 5;

    hipLaunchKernelGGL(convert_weights_kernel, dim3((WS_TOTAL + 255) / 256), dim3(256), 0, stream,
                       W_ih, W_hh, henc_W, dec_W, ws);
    int blocks = (N + 63) / 64;
    hipLaunchKernelGGL(fused_rnn_kernel, dim3(blocks), dim3(256), 0, stream,
                       pos, h_other, h, enc_W, enc_b, henc_b, b_ih, b_hh, dec_b,
                       ws, out, hnew, N);
}